// Round 24
// baseline (248.501 us; speedup 1.0000x reference)
//
#include <hip/hip_runtime.h>
#include <hip/hip_cooperative_groups.h>

namespace cg = cooperative_groups;

#define IN_CH 128
#define HID 64
#define ELLW 32        // 32 slots per node row (in LDS)
#define SPILLCAP 4096  // global overflow edges (BCAP overflow; P ~ 0)
#define LSPCAP 128     // block-local ELL-overflow edges (deg>32)
#define NSCAT 256      // scatter units
#define BCAP 3584      // fixed region capacity per 256-node bucket

typedef short v8s __attribute__((ext_vector_type(8)));   // 8 bf16 (4 VGPRs)
typedef float v4f __attribute__((ext_vector_type(4)));   // 4 f32 acc

__device__ __forceinline__ unsigned int bf16pair(float a, float b) {
    unsigned int ua = __float_as_uint(a);
    unsigned int ub = __float_as_uint(b);
    ua = (ua + 0x7fffu + ((ua >> 16) & 1u)) >> 16;
    ub = (ub + 0x7fffu + ((ub >> 16) & 1u)) & 0xffff0000u;
    return ua | ub;
}
__device__ __forceinline__ unsigned short bf16of(float a) {
    unsigned int ua = __float_as_uint(a);
    return (unsigned short)((ua + 0x7fffu + ((ua >> 16) & 1u)) >> 16);
}

// ===========================================================================
// COOPERATIVE MEGA-KERNEL: prep -> grid.sync -> encode+scatter -> grid.sync
// -> bucket_gather_decode. One launch, zero inter-kernel gaps.
// 256 threads/block; grid-stride unit loops; barriers block-uniform.
// ===========================================================================
__global__ __launch_bounds__(256, 6) void graphmae_fused(
    const float* __restrict__ x, const int* __restrict__ ei,
    const float* __restrict__ W_rel, const float* __restrict__ b_rel,
    const float* __restrict__ W_root, const float* __restrict__ W_dec,
    const float* __restrict__ b_dec, float* __restrict__ out,
    unsigned short* __restrict__ y16, unsigned short* __restrict__ agg16,
    unsigned int* __restrict__ sorted, int* __restrict__ bucketcur,
    int* __restrict__ spillcnt, int2* __restrict__ spill,
    unsigned short* __restrict__ Bt, unsigned short* __restrict__ Wdt,
    int N, int E, int NBUK, int CE)
{
    cg::grid_group grid = cg::this_grid();

    __shared__ int lh[256];                    // scatter hist
    __shared__ int lcur[256];                  // scatter cursors
    __shared__ unsigned short sl[32 * ELLW];   // bgd slot lists
    __shared__ int cnt[32];
    __shared__ int lsp[LSPCAP];
    __shared__ int lspcnt;
    __shared__ unsigned short hs[32][72];      // bgd h rows (padded)

    const int t  = threadIdx.x;
    const int GD = gridDim.x;

    // ---------------- Phase P: prep ----------------
    for (int idx = blockIdx.x * 256 + t; idx < 24576; idx += GD * 256) {
        if (idx < 16384) {
            const int k = idx >> 7, c = idx & 127;
            const float v = (c < HID) ? W_rel[(size_t)k * HID + c]
                                      : W_root[(size_t)k * HID + (c - HID)];
            Bt[(size_t)c * 128 + k] = bf16of(v);
        } else {
            const int j = idx - 16384;
            const int k = j >> 7, c = j & 127;
            Wdt[(size_t)c * 64 + k] = bf16of(W_dec[(size_t)k * IN_CH + c]);
        }
    }
    for (int idx = blockIdx.x * 256 + t; idx < NBUK + 1; idx += GD * 256) {
        if (idx < NBUK) bucketcur[idx] = 0;
        else *spillcnt = 0;
    }
    grid.sync();

    // ---------------- Phase E: scatter units (0..255) + GEMM units ----------
    const int NUNITE = NSCAT + ((N + 63) >> 6);
    for (int u = blockIdx.x; u < NUNITE; u += GD) {
        if (u < NSCAT) {
            // ---- scatter unit ----
            lh[t] = 0; lcur[t] = 0;
            __syncthreads();
            const int e0 = u * CE, e1 = min(E, e0 + CE);
            for (int e = e0 + t; e < e1; e += 256)
                atomicAdd(&lh[ei[E + e] >> 8], 1);
            __syncthreads();
            if (t < NBUK) {
                const int c0 = lh[t];
                if (c0 > 0) lcur[t] = atomicAdd(&bucketcur[t], c0);
            }
            __syncthreads();
            for (int e = e0 + t; e < e1; e += 256) {
                const int d = ei[E + e];
                const int s = ei[e];
                const int bb = d >> 8;
                const int pos = atomicAdd(&lcur[bb], 1);
                if (pos < BCAP) {
                    sorted[(size_t)bb * BCAP + pos] =
                        ((unsigned)(d & 255) << 16) | (unsigned)s;
                } else {
                    const int p = atomicAdd(spillcnt, 1);
                    if (p < SPILLCAP) spill[p] = make_int2(d, s);
                }
            }
        } else {
            // ---- LDS-free MFMA GEMM unit (R23 proven, operand-swapped) ----
            const int n0   = (u - NSCAT) * 64;
            const int w    = t >> 6;
            const int lane = t & 63;
            const int mr   = lane & 15;
            const int kg   = lane >> 4;
            const int nrow = n0 + w * 16 + mr;

            v8s xfrag[4];
            #pragma unroll
            for (int ks = 0; ks < 4; ++ks) {
                uint4 pk = make_uint4(0u, 0u, 0u, 0u);
                if (nrow < N) {
                    const float* xp = x + (size_t)nrow * IN_CH + ks * 32 + kg * 8;
                    const float4 u0 = *(const float4*)(xp);
                    const float4 u1 = *(const float4*)(xp + 4);
                    pk = make_uint4(bf16pair(u0.x, u0.y), bf16pair(u0.z, u0.w),
                                    bf16pair(u1.x, u1.y), bf16pair(u1.z, u1.w));
                }
                xfrag[ks] = *(v8s*)&pk;
            }

            #pragma unroll
            for (int ct = 0; ct < 8; ++ct) {
                v4f acc = {0.f, 0.f, 0.f, 0.f};
                const unsigned short* bp = Bt + (size_t)(ct * 16 + mr) * 128 + kg * 8;
                #pragma unroll
                for (int ks = 0; ks < 4; ++ks) {
                    const v8s bb = *(const v8s*)(bp + ks * 32);
                    acc = __builtin_amdgcn_mfma_f32_16x16x32_bf16(bb, xfrag[ks], acc, 0, 0, 0);
                }
                if (nrow < N) {
                    if (ct < 4) {
                        const int c = ct * 16 + kg * 4;
                        *(uint2*)(y16 + (size_t)nrow * HID + c) =
                            make_uint2(bf16pair(acc[0], acc[1]), bf16pair(acc[2], acc[3]));
                    } else {
                        const int c = (ct - 4) * 16 + kg * 4;
                        const float4 br = *(const float4*)(b_rel + c);
                        *(uint2*)(agg16 + (size_t)nrow * HID + c) =
                            make_uint2(bf16pair(acc[0] + br.x, acc[1] + br.y),
                                       bf16pair(acc[2] + br.z, acc[3] + br.w));
                    }
                }
            }
        }
    }
    grid.sync();

    // ---------------- Phase G: fused bucket-fill + gather + decode ----------
    const int NUNITG = NBUK * 8;
    for (int v = blockIdx.x; v < NUNITG; v += GD) {
        const int b   = v >> 3;
        const int spl = v & 7;
        const int dlo = spl * 32;

        if (t < 32) cnt[t] = 0;
        if (t == 32) lspcnt = 0;
        __syncthreads();   // also protects hs/sl of the PREVIOUS iteration

        const int m = min(bucketcur[b], BCAP);
        const unsigned int* src = sorted + (size_t)b * BCAP;
        for (int i = t; i < m; i += 256) {
            const unsigned int vv = src[i];
            const int dl = (int)(vv >> 16) - dlo;
            if ((unsigned)dl < 32u) {
                const int r = atomicAdd(&cnt[dl], 1);
                if (r < ELLW) sl[dl * ELLW + r] = (unsigned short)(vv & 0xffffu);
                else {
                    const int p = atomicAdd(&lspcnt, 1);
                    if (p < LSPCAP) lsp[p] = (dl << 16) | (int)(vv & 0xffffu);
                }
            }
        }
        __syncthreads();

        const int wid  = t >> 6;
        const int lane = t & 63;
        const int es   = lane >> 3;
        const int cl   = lane & 7;
        const int lspN = min(lspcnt, LSPCAP);
        const int spN  = min(*spillcnt, SPILLCAP);

        for (int j = 0; j < 8; ++j) {
            const int dl = wid * 8 + j;
            const int n  = (b << 8) + dlo + dl;
            if (n >= N) continue;   // wave-uniform
            const int c_ = min(cnt[dl], ELLW);
            const unsigned short* sp = sl + dl * ELLW;

            uint4 av = make_uint4(0u, 0u, 0u, 0u);
            if (es == 0) av = *(const uint4*)(agg16 + (size_t)n * HID + cl * 8);

            float acc[8];
            #pragma unroll
            for (int q = 0; q < 8; ++q) acc[q] = 0.f;

            for (int e = es; e < c_; e += 8) {
                const int s = sp[e];
                const uint4 vv = *(const uint4*)(y16 + (size_t)s * HID + cl * 8);
                acc[0] += __uint_as_float(vv.x << 16);
                acc[1] += __uint_as_float(vv.x & 0xffff0000u);
                acc[2] += __uint_as_float(vv.y << 16);
                acc[3] += __uint_as_float(vv.y & 0xffff0000u);
                acc[4] += __uint_as_float(vv.z << 16);
                acc[5] += __uint_as_float(vv.z & 0xffff0000u);
                acc[6] += __uint_as_float(vv.w << 16);
                acc[7] += __uint_as_float(vv.w & 0xffff0000u);
            }
            for (int i = es; i < lspN; i += 8) {
                const int e2 = lsp[i];
                if ((e2 >> 16) == dl) {
                    const int s = e2 & 0xffff;
                    const uint4 vv = *(const uint4*)(y16 + (size_t)s * HID + cl * 8);
                    acc[0] += __uint_as_float(vv.x << 16);
                    acc[1] += __uint_as_float(vv.x & 0xffff0000u);
                    acc[2] += __uint_as_float(vv.y << 16);
                    acc[3] += __uint_as_float(vv.y & 0xffff0000u);
                    acc[4] += __uint_as_float(vv.z << 16);
                    acc[5] += __uint_as_float(vv.z & 0xffff0000u);
                    acc[6] += __uint_as_float(vv.w << 16);
                    acc[7] += __uint_as_float(vv.w & 0xffff0000u);
                }
            }
            for (int i = es; i < spN; i += 8) {
                const int2 e2 = spill[i];
                if (e2.x == n) {
                    const uint4 vv = *(const uint4*)(y16 + (size_t)e2.y * HID + cl * 8);
                    acc[0] += __uint_as_float(vv.x << 16);
                    acc[1] += __uint_as_float(vv.x & 0xffff0000u);
                    acc[2] += __uint_as_float(vv.y << 16);
                    acc[3] += __uint_as_float(vv.y & 0xffff0000u);
                    acc[4] += __uint_as_float(vv.z << 16);
                    acc[5] += __uint_as_float(vv.z & 0xffff0000u);
                    acc[6] += __uint_as_float(vv.w << 16);
                    acc[7] += __uint_as_float(vv.w & 0xffff0000u);
                }
            }

            #pragma unroll
            for (int mk = 8; mk <= 32; mk <<= 1) {
                #pragma unroll
                for (int q = 0; q < 8; ++q) acc[q] += __shfl_xor(acc[q], mk);
            }

            if (es == 0) {
                const float h0 = fmaxf(__uint_as_float(av.x << 16)          + acc[0], 0.f);
                const float h1 = fmaxf(__uint_as_float(av.x & 0xffff0000u) + acc[1], 0.f);
                const float h2 = fmaxf(__uint_as_float(av.y << 16)          + acc[2], 0.f);
                const float h3 = fmaxf(__uint_as_float(av.y & 0xffff0000u) + acc[3], 0.f);
                const float h4 = fmaxf(__uint_as_float(av.z << 16)          + acc[4], 0.f);
                const float h5 = fmaxf(__uint_as_float(av.z & 0xffff0000u) + acc[5], 0.f);
                const float h6 = fmaxf(__uint_as_float(av.w << 16)          + acc[6], 0.f);
                const float h7 = fmaxf(__uint_as_float(av.w & 0xffff0000u) + acc[7], 0.f);
                uint4 o;
                o.x = bf16pair(h0, h1);
                o.y = bf16pair(h2, h3);
                o.z = bf16pair(h4, h5);
                o.w = bf16pair(h6, h7);
                *(uint4*)(&hs[dl][cl * 8]) = o;
            }
        }
        __syncthreads();   // hs complete

        // decode MFMA from hs
        const int mr   = lane & 15;
        const int kg   = lane >> 4;
        const int tile = wid & 1;
        const int ct0  = (wid >> 1) * 4;
        const int nrow = (b << 8) + dlo + tile * 16 + mr;

        v8s hfrag[2];
        #pragma unroll
        for (int ks = 0; ks < 2; ++ks)
            hfrag[ks] = *(const v8s*)(&hs[tile * 16 + mr][ks * 32 + kg * 8]);

        #pragma unroll
        for (int ct = ct0; ct < ct0 + 4; ++ct) {
            v4f acc = {0.f, 0.f, 0.f, 0.f};
            const unsigned short* wp = Wdt + (size_t)(ct * 16 + mr) * 64 + kg * 8;
            #pragma unroll
            for (int ks = 0; ks < 2; ++ks) {
                const v8s bb = *(const v8s*)(wp + ks * 32);
                acc = __builtin_amdgcn_mfma_f32_16x16x32_bf16(bb, hfrag[ks], acc, 0, 0, 0);
            }
            if (nrow < N) {
                const int c = ct * 16 + kg * 4;
                const float4 bd = *(const float4*)(b_dec + c);
                *(float4*)(out + (size_t)nrow * IN_CH + c) =
                    make_float4(acc[0] + bd.x, acc[1] + bd.y,
                                acc[2] + bd.z, acc[3] + bd.w);
            }
        }
        // next iteration's top barrier protects hs/sl reuse
    }
}

// ===========================================================================
// FALLBACK PATH — the proven R23 3-kernel pipeline (used only if the
// cooperative launch is rejected by the runtime).
// ===========================================================================
__global__ __launch_bounds__(256) void graphmae_prep(
    const float* __restrict__ W_rel, const float* __restrict__ W_root,
    const float* __restrict__ W_dec,
    unsigned short* __restrict__ Bt, unsigned short* __restrict__ Wdt,
    int* __restrict__ bucketcur, int NZ)
{
    const int idx = blockIdx.x * 256 + threadIdx.x;
    if (idx < NZ) bucketcur[idx] = 0;
    if (idx < 16384) {
        const int k = idx >> 7, c = idx & 127;
        const float v = (c < HID) ? W_rel[(size_t)k * HID + c]
                                  : W_root[(size_t)k * HID + (c - HID)];
        Bt[(size_t)c * 128 + k] = bf16of(v);
    } else if (idx < 24576) {
        const int j = idx - 16384;
        const int k = j >> 7, c = j & 127;
        Wdt[(size_t)c * 64 + k] = bf16of(W_dec[(size_t)k * IN_CH + c]);
    }
}

__global__ __launch_bounds__(512) void graphmae_encode_scatter(
    const float* __restrict__ x, const unsigned short* __restrict__ Bt,
    const float* __restrict__ b_rel, const int* __restrict__ ei,
    unsigned short* __restrict__ y16, unsigned short* __restrict__ agg16,
    int* __restrict__ bucketcur, unsigned int* __restrict__ sorted,
    int* __restrict__ spillcnt, int2* __restrict__ spill,
    int N, int E, int NBUK, int CE)
{
    __shared__ int lh[256];
    __shared__ int lcur[256];

    const int t  = threadIdx.x;
    const int n0 = blockIdx.x * 64;
    const bool sduty = (blockIdx.x < NSCAT);
    const int e0 = blockIdx.x * CE;
    const int e1 = sduty ? min(E, e0 + CE) : 0;

    if (t >= 256) { lh[t - 256] = 0; lcur[t - 256] = 0; }
    __syncthreads();

    if (t < 256) {
        const int w    = t >> 6;
        const int lane = t & 63;
        const int mr   = lane & 15;
        const int kg   = lane >> 4;
        const int nrow = n0 + w * 16 + mr;

        v8s xfrag[4];
        #pragma unroll
        for (int ks = 0; ks < 4; ++ks) {
            uint4 pk = make_uint4(0u, 0u, 0u, 0u);
            if (nrow < N) {
                const float* xp = x + (size_t)nrow * IN_CH + ks * 32 + kg * 8;
                const float4 u0 = *(const float4*)(xp);
                const float4 u1 = *(const float4*)(xp + 4);
                pk = make_uint4(bf16pair(u0.x, u0.y), bf16pair(u0.z, u0.w),
                                bf16pair(u1.x, u1.y), bf16pair(u1.z, u1.w));
            }
            xfrag[ks] = *(v8s*)&pk;
        }

        #pragma unroll
        for (int ct = 0; ct < 8; ++ct) {
            v4f acc = {0.f, 0.f, 0.f, 0.f};
            const unsigned short* bp = Bt + (size_t)(ct * 16 + mr) * 128 + kg * 8;
            #pragma unroll
            for (int ks = 0; ks < 4; ++ks) {
                const v8s bb = *(const v8s*)(bp + ks * 32);
                acc = __builtin_amdgcn_mfma_f32_16x16x32_bf16(bb, xfrag[ks], acc, 0, 0, 0);
            }
            if (nrow < N) {
                if (ct < 4) {
                    const int c = ct * 16 + kg * 4;
                    *(uint2*)(y16 + (size_t)nrow * HID + c) =
                        make_uint2(bf16pair(acc[0], acc[1]), bf16pair(acc[2], acc[3]));
                } else {
                    const int c = (ct - 4) * 16 + kg * 4;
                    const float4 br = *(const float4*)(b_rel + c);
                    *(uint2*)(agg16 + (size_t)nrow * HID + c) =
                        make_uint2(bf16pair(acc[0] + br.x, acc[1] + br.y),
                                   bf16pair(acc[2] + br.z, acc[3] + br.w));
                }
            }
        }
    } else if (sduty) {
        for (int e = e0 + (t - 256); e < e1; e += 256)
            atomicAdd(&lh[ei[E + e] >> 8], 1);
    }
    __syncthreads();

    if (t >= 256 && sduty) {
        const int b = t - 256;
        if (b < NBUK) {
            const int c0 = lh[b];
            if (c0 > 0) lcur[b] = atomicAdd(&bucketcur[b], c0);
        }
    }
    __syncthreads();

    if (t >= 256 && sduty) {
        for (int e = e0 + (t - 256); e < e1; e += 256) {
            const int d = ei[E + e];
            const int s = ei[e];
            const int b = d >> 8;
            const int pos = atomicAdd(&lcur[b], 1);
            if (pos < BCAP) {
                sorted[(size_t)b * BCAP + pos] =
                    ((unsigned)(d & 255) << 16) | (unsigned)s;
            } else {
                const int p = atomicAdd(spillcnt, 1);
                if (p < SPILLCAP) spill[p] = make_int2(d, s);
            }
        }
    }
}

__global__ __launch_bounds__(256) void bucket_gather_decode(
    const unsigned int* __restrict__ sorted, const int* __restrict__ bucketcur,
    const unsigned short* __restrict__ y16, const unsigned short* __restrict__ agg16,
    const int* __restrict__ spillcnt, const int2* __restrict__ spill,
    const unsigned short* __restrict__ Wdt, const float* __restrict__ b_dec,
    float* __restrict__ out, int N)
{
    __shared__ unsigned short sl[32 * ELLW];
    __shared__ int cnt[32];
    __shared__ int lsp[LSPCAP];
    __shared__ int lspcnt;
    __shared__ unsigned short hs[32][72];

    const int t   = threadIdx.x;
    const int b   = blockIdx.x >> 3;
    const int spl = blockIdx.x & 7;
    const int dlo = spl * 32;

    if (t < 32) cnt[t] = 0;
    if (t == 32) lspcnt = 0;
    __syncthreads();

    const int m = min(bucketcur[b], BCAP);
    const unsigned int* src = sorted + (size_t)b * BCAP;
    for (int i = t; i < m; i += 256) {
        const unsigned int v = src[i];
        const int dl = (int)(v >> 16) - dlo;
        if ((unsigned)dl < 32u) {
            const int r = atomicAdd(&cnt[dl], 1);
            if (r < ELLW) sl[dl * ELLW + r] = (unsigned short)(v & 0xffffu);
            else {
                const int p = atomicAdd(&lspcnt, 1);
                if (p < LSPCAP) lsp[p] = (dl << 16) | (int)(v & 0xffffu);
            }
        }
    }
    __syncthreads();

    const int wid  = t >> 6;
    const int lane = t & 63;
    const int es   = lane >> 3;
    const int cl   = lane & 7;
    const int lspN = min(lspcnt, LSPCAP);
    const int spN  = min(*spillcnt, SPILLCAP);

    for (int j = 0; j < 8; ++j) {
        const int dl = wid * 8 + j;
        const int n  = (b << 8) + dlo + dl;
        if (n >= N) continue;
        const int c_ = min(cnt[dl], ELLW);
        const unsigned short* sp = sl + dl * ELLW;

        uint4 av = make_uint4(0u, 0u, 0u, 0u);
        if (es == 0) av = *(const uint4*)(agg16 + (size_t)n * HID + cl * 8);

        float acc[8];
        #pragma unroll
        for (int q = 0; q < 8; ++q) acc[q] = 0.f;

        for (int e = es; e < c_; e += 8) {
            const int s = sp[e];
            const uint4 v = *(const uint4*)(y16 + (size_t)s * HID + cl * 8);
            acc[0] += __uint_as_float(v.x << 16);
            acc[1] += __uint_as_float(v.x & 0xffff0000u);
            acc[2] += __uint_as_float(v.y << 16);
            acc[3] += __uint_as_float(v.y & 0xffff0000u);
            acc[4] += __uint_as_float(v.z << 16);
            acc[5] += __uint_as_float(v.z & 0xffff0000u);
            acc[6] += __uint_as_float(v.w << 16);
            acc[7] += __uint_as_float(v.w & 0xffff0000u);
        }
        for (int i = es; i < lspN; i += 8) {
            const int e2 = lsp[i];
            if ((e2 >> 16) == dl) {
                const int s = e2 & 0xffff;
                const uint4 v = *(const uint4*)(y16 + (size_t)s * HID + cl * 8);
                acc[0] += __uint_as_float(v.x << 16);
                acc[1] += __uint_as_float(v.x & 0xffff0000u);
                acc[2] += __uint_as_float(v.y << 16);
                acc[3] += __uint_as_float(v.y & 0xffff0000u);
                acc[4] += __uint_as_float(v.z << 16);
                acc[5] += __uint_as_float(v.z & 0xffff0000u);
                acc[6] += __uint_as_float(v.w << 16);
                acc[7] += __uint_as_float(v.w & 0xffff0000u);
            }
        }
        for (int i = es; i < spN; i += 8) {
            const int2 e2 = spill[i];
            if (e2.x == n) {
                const uint4 v = *(const uint4*)(y16 + (size_t)e2.y * HID + cl * 8);
                acc[0] += __uint_as_float(v.x << 16);
                acc[1] += __uint_as_float(v.x & 0xffff0000u);
                acc[2] += __uint_as_float(v.y << 16);
                acc[3] += __uint_as_float(v.y & 0xffff0000u);
                acc[4] += __uint_as_float(v.z << 16);
                acc[5] += __uint_as_float(v.z & 0xffff0000u);
                acc[6] += __uint_as_float(v.w << 16);
                acc[7] += __uint_as_float(v.w & 0xffff0000u);
            }
        }

        #pragma unroll
        for (int mk = 8; mk <= 32; mk <<= 1) {
            #pragma unroll
            for (int q = 0; q < 8; ++q) acc[q] += __shfl_xor(acc[q], mk);
        }

        if (es == 0) {
            const float h0 = fmaxf(__uint_as_float(av.x << 16)          + acc[0], 0.f);
            const float h1 = fmaxf(__uint_as_float(av.x & 0xffff0000u) + acc[1], 0.f);
            const float h2 = fmaxf(__uint_as_float(av.y << 16)          + acc[2], 0.f);
            const float h3 = fmaxf(__uint_as_float(av.y & 0xffff0000u) + acc[3], 0.f);
            const float h4 = fmaxf(__uint_as_float(av.z << 16)          + acc[4], 0.f);
            const float h5 = fmaxf(__uint_as_float(av.z & 0xffff0000u) + acc[5], 0.f);
            const float h6 = fmaxf(__uint_as_float(av.w << 16)          + acc[6], 0.f);
            const float h7 = fmaxf(__uint_as_float(av.w & 0xffff0000u) + acc[7], 0.f);
            uint4 o;
            o.x = bf16pair(h0, h1);
            o.y = bf16pair(h2, h3);
            o.z = bf16pair(h4, h5);
            o.w = bf16pair(h6, h7);
            *(uint4*)(&hs[dl][cl * 8]) = o;
        }
    }
    __syncthreads();

    const int mr   = lane & 15;
    const int kg   = lane >> 4;
    const int tile = wid & 1;
    const int ct0  = (wid >> 1) * 4;
    const int nrow = (b << 8) + dlo + tile * 16 + mr;

    v8s hfrag[2];
    #pragma unroll
    for (int ks = 0; ks < 2; ++ks)
        hfrag[ks] = *(const v8s*)(&hs[tile * 16 + mr][ks * 32 + kg * 8]);

    #pragma unroll
    for (int ct = ct0; ct < ct0 + 4; ++ct) {
        v4f acc = {0.f, 0.f, 0.f, 0.f};
        const unsigned short* wp = Wdt + (size_t)(ct * 16 + mr) * 64 + kg * 8;
        #pragma unroll
        for (int ks = 0; ks < 2; ++ks) {
            const v8s bb = *(const v8s*)(wp + ks * 32);
            acc = __builtin_amdgcn_mfma_f32_16x16x32_bf16(bb, hfrag[ks], acc, 0, 0, 0);
        }
        if (nrow < N) {
            const int c = ct * 16 + kg * 4;
            const float4 bd = *(const float4*)(b_dec + c);
            *(float4*)(out + (size_t)nrow * IN_CH + c) =
                make_float4(acc[0] + bd.x, acc[1] + bd.y,
                            acc[2] + bd.z, acc[3] + bd.w);
        }
    }
}

// ---------------------------------------------------------------------------
extern "C" void kernel_launch(void* const* d_in, const int* in_sizes, int n_in,
                              void* d_out, int out_size, void* d_ws, size_t ws_size,
                              hipStream_t stream)
{
    const float* x      = (const float*)d_in[0];
    const int*   ei     = (const int*)  d_in[1];
    const float* W_rel  = (const float*)d_in[2];
    const float* b_rel  = (const float*)d_in[3];
    const float* W_root = (const float*)d_in[4];
    const float* W_dec  = (const float*)d_in[5];
    const float* b_dec  = (const float*)d_in[6];
    float* out = (float*)d_out;

    const int N = in_sizes[0] / IN_CH;
    const int E = in_sizes[1] / 2;

    const int NBUK = (N + 255) / 256;      // 196
    const int CE   = (E + NSCAT - 1) / NSCAT;

    unsigned short* y16   = (unsigned short*)d_ws;                    // [N][64]
    unsigned short* agg16 = y16 + (size_t)N * HID;                    // [N][64]
    unsigned int* sorted  = (unsigned int*)(agg16 + (size_t)N * HID); // [NBUK*BCAP]
    int* bucketcur = (int*)(sorted + (size_t)NBUK * BCAP);            // [NBUK]
    int* spillcnt  = bucketcur + NBUK;                                // [1]+pad
    int2* spill    = (int2*)(spillcnt + 3);                           // [SPILLCAP]
    unsigned short* Bt  = (unsigned short*)(spill + SPILLCAP);        // [128*128]
    unsigned short* Wdt = Bt + 128 * 128;                             // [128*64]

    // ---- try the cooperative mega-kernel ----
    int mb = 0;
    hipError_t qe = hipOccupancyMaxActiveBlocksPerMultiprocessor(
        &mb, graphmae_fused, 256, 0);
    int g = (qe == hipSuccess && mb > 0) ? mb * 256 : 0;   // 256 CUs (gfx950)
    if (g > NBUK * 8) g = NBUK * 8;                        // no benefit past 1568

    hipError_t le = hipErrorUnknown;
    if (g >= 256) {
        int Ni = N, Ei = E, NBUKi = NBUK, CEi = CE;
        void* args[] = {
            (void*)&x, (void*)&ei, (void*)&W_rel, (void*)&b_rel,
            (void*)&W_root, (void*)&W_dec, (void*)&b_dec, (void*)&out,
            (void*)&y16, (void*)&agg16, (void*)&sorted, (void*)&bucketcur,
            (void*)&spillcnt, (void*)&spill, (void*)&Bt, (void*)&Wdt,
            (void*)&Ni, (void*)&Ei, (void*)&NBUKi, (void*)&CEi };
        le = hipLaunchCooperativeKernel((void*)graphmae_fused,
                                        dim3(g), dim3(256), args, 0, stream);
    }

    if (le != hipSuccess) {
        // ---- fallback: proven R23 3-kernel pipeline ----
        const int nblk64 = (N + 63) / 64;
        graphmae_prep<<<96, 256, 0, stream>>>(W_rel, W_root, W_dec, Bt, Wdt,
                                              bucketcur, NBUK + 1);
        graphmae_encode_scatter<<<nblk64, 512, 0, stream>>>(
            x, Bt, b_rel, ei, y16, agg16,
            bucketcur, sorted, spillcnt, spill, N, E, NBUK, CE);
        bucket_gather_decode<<<NBUK * 8, 256, 0, stream>>>(
            sorted, bucketcur, y16, agg16, spillcnt, spill, Wdt, b_dec, out, N);
    }
}

// Round 25
// 71.012 us; speedup vs baseline: 3.4994x; 3.4994x over previous
//
#include <hip/hip_runtime.h>

#define IN_CH 128
#define HID 64
#define ELLW 32        // 32 slots per node row (in LDS)
#define SPILLCAP 4096  // global overflow edges (BCAP overflow; P ~ 0)
#define LSPCAP 128     // block-local ELL-overflow edges (deg>32)
#define NSCAT 256      // blocks carrying scatter duty
#define BCAP 3584      // fixed region capacity per 256-node bucket (mean 3061, +9 sigma)

typedef short v8s __attribute__((ext_vector_type(8)));   // 8 bf16 (4 VGPRs)
typedef float v4f __attribute__((ext_vector_type(4)));   // 4 f32 acc

// branch-free f32 -> bf16 (round-to-nearest-even), pure uint math
__device__ __forceinline__ unsigned int bf16pair(float a, float b) {
    unsigned int ua = __float_as_uint(a);
    unsigned int ub = __float_as_uint(b);
    ua = (ua + 0x7fffu + ((ua >> 16) & 1u)) >> 16;          // elem0 -> low 16
    ub = (ub + 0x7fffu + ((ub >> 16) & 1u)) & 0xffff0000u;  // elem1 -> high 16
    return ua | ub;
}
__device__ __forceinline__ unsigned short bf16of(float a) {
    unsigned int ua = __float_as_uint(a);
    return (unsigned short)((ua + 0x7fffu + ((ua >> 16) & 1u)) >> 16);
}

// ---------------------------------------------------------------------------
// Kernel 0: prep. Bt = [W_rel|W_root]^T (bf16 [c:128][k:128], 32KB) and
// Wdt = W_dec^T (bf16 [c:128][k:64], 16KB). Zeroes bucketcur+spillcnt.
// ---------------------------------------------------------------------------
__global__ __launch_bounds__(256) void graphmae_prep(
    const float* __restrict__ W_rel, const float* __restrict__ W_root,
    const float* __restrict__ W_dec,
    unsigned short* __restrict__ Bt, unsigned short* __restrict__ Wdt,
    int* __restrict__ bucketcur, int NZ)
{
    const int idx = blockIdx.x * 256 + threadIdx.x;   // 0..24575
    if (idx < NZ) bucketcur[idx] = 0;
    if (idx < 16384) {
        const int k = idx >> 7;      // 0..127
        const int c = idx & 127;     // 0..127
        const float v = (c < HID) ? W_rel[(size_t)k * HID + c]
                                  : W_root[(size_t)k * HID + (c - HID)];
        Bt[(size_t)c * 128 + k] = bf16of(v);
    } else if (idx < 24576) {
        const int j = idx - 16384;
        const int k = j >> 7;        // 0..63
        const int c = j & 127;       // 0..127
        Wdt[(size_t)c * 64 + k] = bf16of(W_dec[(size_t)k * IN_CH + c]);
    }
}

// ---------------------------------------------------------------------------
// Kernel 1: LDS-free MFMA encoder + co-resident bucket scatter (proven
// R20-R23). Operand-swapped MFMA -> D=(x@W)^T -> lane owns one node, 4
// contiguous output cols per ct -> vector epilogue stores. agg bf16.
// ---------------------------------------------------------------------------
__global__ __launch_bounds__(512) void graphmae_encode_scatter(
    const float* __restrict__ x, const unsigned short* __restrict__ Bt,
    const float* __restrict__ b_rel, const int* __restrict__ ei,
    unsigned short* __restrict__ y16, unsigned short* __restrict__ agg16,
    int* __restrict__ bucketcur, unsigned int* __restrict__ sorted,
    int* __restrict__ spillcnt, int2* __restrict__ spill,
    int N, int E, int NBUK, int CE)
{
    __shared__ int lh[256];    // scatter: per-bucket local count
    __shared__ int lcur[256];  // scatter: reserved base -> running cursor

    const int t  = threadIdx.x;
    const int n0 = blockIdx.x * 64;
    const bool sduty = (blockIdx.x < NSCAT);
    const int e0 = blockIdx.x * CE;
    const int e1 = sduty ? min(E, e0 + CE) : 0;

    if (t >= 256) { lh[t - 256] = 0; lcur[t - 256] = 0; }
    __syncthreads();   // B1: lh zeroed

    if (t < 256) {
        const int w    = t >> 6;
        const int lane = t & 63;
        const int mr   = lane & 15;
        const int kg   = lane >> 4;
        const int nrow = n0 + w * 16 + mr;   // this lane's node (D col)

        v8s xfrag[4];
        #pragma unroll
        for (int ks = 0; ks < 4; ++ks) {
            uint4 pk = make_uint4(0u, 0u, 0u, 0u);
            if (nrow < N) {
                const float* xp = x + (size_t)nrow * IN_CH + ks * 32 + kg * 8;
                const float4 u0 = *(const float4*)(xp);
                const float4 u1 = *(const float4*)(xp + 4);
                pk = make_uint4(bf16pair(u0.x, u0.y), bf16pair(u0.z, u0.w),
                                bf16pair(u1.x, u1.y), bf16pair(u1.z, u1.w));
            }
            xfrag[ks] = *(v8s*)&pk;
        }

        #pragma unroll
        for (int ct = 0; ct < 8; ++ct) {
            v4f acc = {0.f, 0.f, 0.f, 0.f};
            const unsigned short* bp = Bt + (size_t)(ct * 16 + mr) * 128 + kg * 8;
            #pragma unroll
            for (int ks = 0; ks < 4; ++ks) {
                const v8s b = *(const v8s*)(bp + ks * 32);
                acc = __builtin_amdgcn_mfma_f32_16x16x32_bf16(b, xfrag[ks], acc, 0, 0, 0);
            }
            if (nrow < N) {
                if (ct < 4) {
                    const int c = ct * 16 + kg * 4;
                    *(uint2*)(y16 + (size_t)nrow * HID + c) =
                        make_uint2(bf16pair(acc[0], acc[1]), bf16pair(acc[2], acc[3]));
                } else {
                    const int c = (ct - 4) * 16 + kg * 4;
                    const float4 br = *(const float4*)(b_rel + c);
                    *(uint2*)(agg16 + (size_t)nrow * HID + c) =
                        make_uint2(bf16pair(acc[0] + br.x, acc[1] + br.y),
                                   bf16pair(acc[2] + br.z, acc[3] + br.w));
                }
            }
        }
    } else if (sduty) {
        for (int e = e0 + (t - 256); e < e1; e += 256)
            atomicAdd(&lh[ei[E + e] >> 8], 1);
    }
    __syncthreads();   // B2: hist complete

    if (t >= 256 && sduty) {
        const int b = t - 256;
        if (b < NBUK) {
            const int cnt = lh[b];
            if (cnt > 0) lcur[b] = atomicAdd(&bucketcur[b], cnt);
        }
    }
    __syncthreads();   // B3: cursors ready

    if (t >= 256 && sduty) {
        for (int e = e0 + (t - 256); e < e1; e += 256) {
            const int d = ei[E + e];
            const int s = ei[e];
            const int b = d >> 8;
            const int pos = atomicAdd(&lcur[b], 1);
            if (pos < BCAP) {
                sorted[(size_t)b * BCAP + pos] =
                    ((unsigned)(d & 255) << 16) | (unsigned)s;
            } else {
                const int p = atomicAdd(spillcnt, 1);   // statistically never
                if (p < SPILLCAP) spill[p] = make_int2(d, s);
            }
        }
    }
}

// ---------------------------------------------------------------------------
// Kernel 2: FUSED bucket-fill + gather + decode (proven R22/R23 structure).
// ---------------------------------------------------------------------------
__global__ __launch_bounds__(256) void bucket_gather_decode(
    const unsigned int* __restrict__ sorted, const int* __restrict__ bucketcur,
    const unsigned short* __restrict__ y16, const unsigned short* __restrict__ agg16,
    const int* __restrict__ spillcnt, const int2* __restrict__ spill,
    const unsigned short* __restrict__ Wdt, const float* __restrict__ b_dec,
    float* __restrict__ out, int N)
{
    __shared__ unsigned short sl[32 * ELLW];   // 2KB slot lists
    __shared__ int cnt[32];
    __shared__ int lsp[LSPCAP];                // local overflow: (dl<<16)|s
    __shared__ int lspcnt;
    __shared__ unsigned short hs[32][72];      // h rows bf16, padded (+8)

    const int t   = threadIdx.x;
    const int b   = blockIdx.x >> 3;     // bucket
    const int spl = blockIdx.x & 7;      // split
    const int dlo = spl * 32;            // own local-dst range [dlo, dlo+32)

    if (t < 32) cnt[t] = 0;
    if (t == 32) lspcnt = 0;
    __syncthreads();

    // ---- phase 1: scan bucket segment, keep own nodes ----
    const int m = min(bucketcur[b], BCAP);
    const unsigned int* src = sorted + (size_t)b * BCAP;
    for (int i = t; i < m; i += 256) {
        const unsigned int v = src[i];
        const int dl = (int)(v >> 16) - dlo;
        if ((unsigned)dl < 32u) {
            const int r = atomicAdd(&cnt[dl], 1);
            if (r < ELLW) {
                sl[dl * ELLW + r] = (unsigned short)(v & 0xffffu);
            } else {
                const int p = atomicAdd(&lspcnt, 1);   // P ~ 2e-3 graph-wide
                if (p < LSPCAP) lsp[p] = (dl << 16) | (int)(v & 0xffffu);
            }
        }
    }
    __syncthreads();

    // ---- phase 2: 4 waves x 8 nodes, gather; h -> hs ----
    const int wid  = t >> 6;
    const int lane = t & 63;
    const int es   = lane >> 3;   // edge slot 0..7
    const int cl   = lane & 7;    // col group: cols cl*8 .. cl*8+7
    const int lspN = min(lspcnt, LSPCAP);
    const int spN  = min(*spillcnt, SPILLCAP);

    for (int j = 0; j < 8; ++j) {
        const int dl = wid * 8 + j;          // local node 0..31
        const int n  = (b << 8) + dlo + dl;
        if (n >= N) continue;                // wave-uniform
        const int c_ = min(cnt[dl], ELLW);
        const unsigned short* sp = sl + dl * ELLW;

        // early independent agg read (bf16, only writer lanes)
        uint4 av = make_uint4(0u, 0u, 0u, 0u);
        if (es == 0) av = *(const uint4*)(agg16 + (size_t)n * HID + cl * 8);

        float acc[8];
        #pragma unroll
        for (int q = 0; q < 8; ++q) acc[q] = 0.f;

        for (int e = es; e < c_; e += 8) {
            const int s = sp[e];
            const uint4 v = *(const uint4*)(y16 + (size_t)s * HID + cl * 8);
            acc[0] += __uint_as_float(v.x << 16);
            acc[1] += __uint_as_float(v.x & 0xffff0000u);
            acc[2] += __uint_as_float(v.y << 16);
            acc[3] += __uint_as_float(v.y & 0xffff0000u);
            acc[4] += __uint_as_float(v.z << 16);
            acc[5] += __uint_as_float(v.z & 0xffff0000u);
            acc[6] += __uint_as_float(v.w << 16);
            acc[7] += __uint_as_float(v.w & 0xffff0000u);
        }
        for (int i = es; i < lspN; i += 8) {
            const int e2 = lsp[i];
            if ((e2 >> 16) == dl) {
                const int s = e2 & 0xffff;
                const uint4 v = *(const uint4*)(y16 + (size_t)s * HID + cl * 8);
                acc[0] += __uint_as_float(v.x << 16);
                acc[1] += __uint_as_float(v.x & 0xffff0000u);
                acc[2] += __uint_as_float(v.y << 16);
                acc[3] += __uint_as_float(v.y & 0xffff0000u);
                acc[4] += __uint_as_float(v.z << 16);
                acc[5] += __uint_as_float(v.z & 0xffff0000u);
                acc[6] += __uint_as_float(v.w << 16);
                acc[7] += __uint_as_float(v.w & 0xffff0000u);
            }
        }
        for (int i = es; i < spN; i += 8) {
            const int2 e2 = spill[i];
            if (e2.x == n) {
                const uint4 v = *(const uint4*)(y16 + (size_t)e2.y * HID + cl * 8);
                acc[0] += __uint_as_float(v.x << 16);
                acc[1] += __uint_as_float(v.x & 0xffff0000u);
                acc[2] += __uint_as_float(v.y << 16);
                acc[3] += __uint_as_float(v.y & 0xffff0000u);
                acc[4] += __uint_as_float(v.z << 16);
                acc[5] += __uint_as_float(v.z & 0xffff0000u);
                acc[6] += __uint_as_float(v.w << 16);
                acc[7] += __uint_as_float(v.w & 0xffff0000u);
            }
        }

        #pragma unroll
        for (int mk = 8; mk <= 32; mk <<= 1) {
            #pragma unroll
            for (int q = 0; q < 8; ++q) acc[q] += __shfl_xor(acc[q], mk);
        }

        if (es == 0) {
            const float h0 = fmaxf(__uint_as_float(av.x << 16)          + acc[0], 0.f);
            const float h1 = fmaxf(__uint_as_float(av.x & 0xffff0000u) + acc[1], 0.f);
            const float h2 = fmaxf(__uint_as_float(av.y << 16)          + acc[2], 0.f);
            const float h3 = fmaxf(__uint_as_float(av.y & 0xffff0000u) + acc[3], 0.f);
            const float h4 = fmaxf(__uint_as_float(av.z << 16)          + acc[4], 0.f);
            const float h5 = fmaxf(__uint_as_float(av.z & 0xffff0000u) + acc[5], 0.f);
            const float h6 = fmaxf(__uint_as_float(av.w << 16)          + acc[6], 0.f);
            const float h7 = fmaxf(__uint_as_float(av.w & 0xffff0000u) + acc[7], 0.f);
            uint4 o;
            o.x = bf16pair(h0, h1);
            o.y = bf16pair(h2, h3);
            o.z = bf16pair(h4, h5);
            o.w = bf16pair(h6, h7);
            *(uint4*)(&hs[dl][cl * 8]) = o;
        }
    }
    __syncthreads();   // hs complete

    // ---- phase 3: decode MFMA from hs (proven operand-swapped form) ----
    const int mr   = lane & 15;
    const int kg   = lane >> 4;
    const int tile = wid & 1;
    const int ct0  = (wid >> 1) * 4;
    const int nrow = (b << 8) + dlo + tile * 16 + mr;

    v8s hfrag[2];
    #pragma unroll
    for (int ks = 0; ks < 2; ++ks)
        hfrag[ks] = *(const v8s*)(&hs[tile * 16 + mr][ks * 32 + kg * 8]);

    #pragma unroll
    for (int ct = ct0; ct < ct0 + 4; ++ct) {
        v4f acc = {0.f, 0.f, 0.f, 0.f};
        const unsigned short* wp = Wdt + (size_t)(ct * 16 + mr) * 64 + kg * 8;
        #pragma unroll
        for (int ks = 0; ks < 2; ++ks) {
            const v8s bb = *(const v8s*)(wp + ks * 32);
            acc = __builtin_amdgcn_mfma_f32_16x16x32_bf16(bb, hfrag[ks], acc, 0, 0, 0);
        }
        if (nrow < N) {
            const int c = ct * 16 + kg * 4;
            const float4 bd = *(const float4*)(b_dec + c);
            *(float4*)(out + (size_t)nrow * IN_CH + c) =
                make_float4(acc[0] + bd.x, acc[1] + bd.y,
                            acc[2] + bd.z, acc[3] + bd.w);
        }
    }
}

// ---------------------------------------------------------------------------
extern "C" void kernel_launch(void* const* d_in, const int* in_sizes, int n_in,
                              void* d_out, int out_size, void* d_ws, size_t ws_size,
                              hipStream_t stream)
{
    const float* x      = (const float*)d_in[0];
    const int*   ei     = (const int*)  d_in[1];   // [2][E] int32
    const float* W_rel  = (const float*)d_in[2];
    const float* b_rel  = (const float*)d_in[3];
    const float* W_root = (const float*)d_in[4];
    const float* W_dec  = (const float*)d_in[5];
    const float* b_dec  = (const float*)d_in[6];
    float* out = (float*)d_out;

    const int N = in_sizes[0] / IN_CH;
    const int E = in_sizes[1] / 2;

    const int NBUK = (N + 255) / 256;      // 196 buckets (dst>>8)
    const int CE   = (E + NSCAT - 1) / NSCAT;

    unsigned short* y16   = (unsigned short*)d_ws;                  // [N][64] bf16
    unsigned short* agg16 = y16 + (size_t)N * HID;                  // [N][64] bf16
    unsigned int* sorted  = (unsigned int*)(agg16 + (size_t)N * HID); // [NBUK*BCAP]
    int* bucketcur = (int*)(sorted + (size_t)NBUK * BCAP);          // [NBUK]
    int* spillcnt  = bucketcur + NBUK;                              // [1]+pad
    int2* spill    = (int2*)(spillcnt + 3);                         // [SPILLCAP]
    unsigned short* Bt  = (unsigned short*)(spill + SPILLCAP);      // [128*128] bf16
    unsigned short* Wdt = Bt + 128 * 128;                           // [128*64] bf16

    const int nblk64 = (N + 63) / 64;   // 782 blocks (>= NSCAT)

    graphmae_prep<<<96, 256, 0, stream>>>(W_rel, W_root, W_dec, Bt, Wdt,
                                          bucketcur, NBUK + 1);

    graphmae_encode_scatter<<<nblk64, 512, 0, stream>>>(
        x, Bt, b_rel, ei, y16, agg16,
        bucketcur, sorted, spillcnt, spill, N, E, NBUK, CE);

    bucket_gather_decode<<<NBUK * 8, 256, 0, stream>>>(
        sorted, bucketcur, y16, agg16, spillcnt, spill, Wdt, b_dec, out, N);
}